// Round 5
// baseline (285.511 us; speedup 1.0000x reference)
//
#include <hip/hip_runtime.h>

#define NN 20000
#define POFF (8 * NN * 64)   // X byte offset for pass=1 (8 k-rows down)

typedef _Float16 f16x2 __attribute__((ext_vector_type(2)));
typedef unsigned short u16x2 __attribute__((ext_vector_type(2)));

union U32H2 { unsigned int u; f16x2 h; };
union U32S2 { unsigned int u; u16x2 s; };

__device__ __forceinline__ f16x2 bc_h2(unsigned int u) { U32H2 x; x.u = u; return x.h; }
__device__ __forceinline__ unsigned int dup_h(float v) {
    _Float16 h = (_Float16)v;
    unsigned short b = __builtin_bit_cast(unsigned short, h);
    return ((unsigned int)b << 16) | b;
}
// packed f32->f16 convert, result as raw u32 (v_cvt_pkrtz_f16_f32)
__device__ __forceinline__ unsigned int pkrtz_u32(float a, float b) {
    return __builtin_bit_cast(unsigned int, __builtin_amdgcn_cvt_pkrtz(a, b));
}
// OR across lane pairs via DPP quad_perm xor1
__device__ __forceinline__ unsigned int or_dpp_x1(unsigned int v) {
    return v | (unsigned int)__builtin_amdgcn_update_dpp(0, (int)v, 0xB1, 0xF, 0xF, true);
}

// ---------------- setup: prep (block 20) + pack (blocks 0..19) ----------------
__global__ __launch_bounds__(1024) void setup_kernel(const float* __restrict__ W,
                                                     const float* __restrict__ a0,
                                                     unsigned int* __restrict__ pi_t_pk,
                                                     unsigned int* __restrict__ pi1_pk,
                                                     unsigned int* __restrict__ pi2_pk,
                                                     unsigned short* __restrict__ T0) {
    const int t = threadIdx.x;
    if (blockIdx.x != 20) {
        // pack a0 fp32 (B,N) -> two u16 planes: plane0=(b0,b1), plane1=(b2,b3)
        int i = blockIdx.x * 1024 + t;
        if (i < NN) {
            unsigned int b0 = __float2uint_rn(__saturatef(a0[i]) * 255.0f);
            unsigned int b1 = __float2uint_rn(__saturatef(a0[NN + i]) * 255.0f);
            unsigned int b2 = __float2uint_rn(__saturatef(a0[2 * NN + i]) * 255.0f);
            unsigned int b3 = __float2uint_rn(__saturatef(a0[3 * NN + i]) * 255.0f);
            T0[i] = (unsigned short)(b0 | (b1 << 8));
            T0[NN + i] = (unsigned short)(b2 | (b3 << 8));
        }
        return;
    }
    __shared__ float red[1024];
    __shared__ float piL[4096];
    float4 wv = ((const float4*)W)[t];
    float m = fmaxf(fmaxf(wv.x, wv.y), fmaxf(wv.z, wv.w));
    red[t] = m; __syncthreads();
    for (int s = 512; s > 0; s >>= 1) {
        if (t < s) red[t] = fmaxf(red[t], red[t + s]);
        __syncthreads();
    }
    m = red[0];
    __syncthreads();
    float e0 = expf(wv.x - m), e1 = expf(wv.y - m);
    float e2 = expf(wv.z - m), e3 = expf(wv.w - m);
    red[t] = e0 + e1 + e2 + e3;
    __syncthreads();
    for (int s = 512; s > 0; s >>= 1) {
        if (t < s) red[t] += red[t + s];
        __syncthreads();
    }
    float inv = 1.0f / red[0];
    float p[4] = { e0 * inv, e1 * inv, e2 * inv, e3 * inv };
#pragma unroll
    for (int i = 0; i < 4; i++) {
        int f = t * 4 + i;
        piL[f] = p[i];
        pi_t_pk[(f & 63) * 64 + (f >> 6)] = dup_h(p[i]);  // transposed [k][j]
    }
    __syncthreads();
    if (t < 64) {
        float s = 0.f;
        for (int k = 0; k < 64; k++) s += piL[t * 64 + k];
        pi1_pk[t] = dup_h(s);
    } else if (t < 128) {
        int k = t - 64;
        float s = 0.f;
        for (int j = 0; j < 64; j++) s += piL[j * 64 + k];
        pi2_pk[k] = dup_h(s);
    }
}

// ---- phase-1 macros: named regs only, 2-batch path ----
#define ADDRC(nb)                                                     \
    do {                                                              \
        int n_;                                                       \
        n_ = (nb) + n8;      lofA = rb64 + (n_ < NN ? n_ : NN - 1) * 64; \
        n_ = (nb) + 8 + n8;  lofB = rb64 + (n_ < NN ? n_ : NN - 1) * 64; \
        n_ = (nb) + 16 + n8; lofC = rb64 + (n_ < NN ? n_ : NN - 1) * 64; \
        n_ = (nb) + 24 + n8; lofD = rb64 + (n_ < NN ? n_ : NN - 1) * 64; \
    } while (0)

#define LDXQ(x0, x1, x2, x3, off)                                     \
    do {                                                              \
        x0 = *(const int4*)(Xrow + (off));                            \
        x1 = *(const int4*)(Xrow + (off) + 16);                       \
        x2 = *(const int4*)(Xrow + (off) + 32);                       \
        x3 = *(const int4*)(Xrow + (off) + 48);                       \
    } while (0)

// one clause pair for 2 batches: u16 gathers -> (b0,b1) u16x2 product -> max
#define GPAIR(ia, ib)                                                 \
    do {                                                              \
        unsigned int gx_ = (unsigned int)tab[ia];                     \
        unsigned int gy_ = (unsigned int)tab[ib];                     \
        unsigned int A_ = __builtin_amdgcn_perm(0u, gx_, 0x0C010C00u); \
        unsigned int B_ = __builtin_amdgcn_perm(0u, gy_, 0x0C010C00u); \
        U32S2 pa_, pb_; pa_.u = A_; pb_.u = B_;                       \
        pa_.s = pa_.s * pb_.s;            /* v_pk_mul_lo_u16 */       \
        mx.s = __builtin_elementwise_max(mx.s, pa_.s);                \
    } while (0)

#define PH1STEP(db, occ, pss, cn, x0, x1, x2, x3)                     \
    do {                                                              \
        if (8 * (occ) < (cn)) {                                       \
            U32S2 mx; mx.u = 0u;                                      \
            GPAIR(x0.x, x0.y); GPAIR(x0.z, x0.w);                     \
            GPAIR(x1.x, x1.y); GPAIR(x1.z, x1.w);                     \
            GPAIR(x2.x, x2.y); GPAIR(x2.z, x2.w);                     \
            GPAIR(x3.x, x3.y); GPAIR(x3.z, x3.w);                     \
            int col_ = (occ) * 8 + n8;                                \
            if (col_ < (cn)) {                                        \
                float f0_ = (float)(mx.u & 0xFFFFu) * sc;             \
                float f1_ = (float)(mx.u >> 16) * sc;                 \
                Ft[db][row0 + (pss) * 8][col_] = pkrtz_u32(f0_, f1_); \
            }                                                         \
        }                                                             \
    } while (0)

#define CPX do { cx0 = nx0; cx1 = nx1; cx2 = nx2; cx3 = nx3; } while (0)

// 8 steps (4 oc x 2 pass), rolling one-step register prefetch (cx holds step 0)
#define PH1CHUNK(db, cn)                                              \
    do {                                                              \
        LDXQ(nx0, nx1, nx2, nx3, lofA + POFF); PH1STEP(db, 0, 0, cn, cx0, cx1, cx2, cx3); CPX; \
        LDXQ(nx0, nx1, nx2, nx3, lofB);        PH1STEP(db, 0, 1, cn, cx0, cx1, cx2, cx3); CPX; \
        LDXQ(nx0, nx1, nx2, nx3, lofB + POFF); PH1STEP(db, 1, 0, cn, cx0, cx1, cx2, cx3); CPX; \
        LDXQ(nx0, nx1, nx2, nx3, lofC);        PH1STEP(db, 1, 1, cn, cx0, cx1, cx2, cx3); CPX; \
        LDXQ(nx0, nx1, nx2, nx3, lofC + POFF); PH1STEP(db, 2, 0, cn, cx0, cx1, cx2, cx3); CPX; \
        LDXQ(nx0, nx1, nx2, nx3, lofD);        PH1STEP(db, 2, 1, cn, cx0, cx1, cx2, cx3); CPX; \
        LDXQ(nx0, nx1, nx2, nx3, lofD + POFF); PH1STEP(db, 3, 0, cn, cx0, cx1, cx2, cx3); CPX; \
        PH1STEP(db, 3, 1, cn, cx0, cx1, cx2, cx3);                    \
    } while (0)

// ---------------- fused predicate_forward iteration ----------------
// Batch-pair split: each block handles 2 of 4 batches -> 78,912 B LDS ->
// 2 blocks/CU. Co-resident blocks run ph1/ph2 decorrelated (independent
// barriers), overlapping LDS-gather latency with the other block's VALU.
// rng = bid&255, pair = bid>>8: pair-blocks of one range share an XCD
// (256 % 8 == 0) so the duplicated X read dedups in that XCD's L2.
template <int ITER>
__global__ __launch_bounds__(512, 4) void fused_iter(
    const unsigned short* __restrict__ Tsrc,   // [2][NN] u16 planes
    const int* __restrict__ X1, const int* __restrict__ X2,
    const unsigned int* __restrict__ pi_t_pk,
    const unsigned int* __restrict__ pi1_pk,
    const unsigned int* __restrict__ pi2_pk,
    const float* __restrict__ a0,
    unsigned short* __restrict__ Tdst, float* __restrict__ outP) {
    __shared__ unsigned short tab[NN];          // 40,000 B
    __shared__ unsigned int Ft[2][128][30];     // 30,720 B (f16x2 = 2 batches)
    __shared__ float redp[2][8][64][2];         //  8,192 B

    const int t = threadIdx.x;
    const int bid = (int)blockIdx.x;
    const int rng = bid & 255;
    const int pair = bid >> 8;                  // 0: batches 0,1; 1: batches 2,3
    const int bstart = rng < 32 ? rng * 79 : 32 * 79 + (rng - 32) * 78;
    const int bcnt = rng < 32 ? 79 : 78;        // chunks: 30,30,(19|18)

    const int wid = t >> 6, lane = t & 63;
    const int widu = __builtin_amdgcn_readfirstlane(wid);   // 0..7
    const int r8 = lane >> 3, n8 = lane & 7;
    const int row0 = widu * 16 + r8;            // + pass*8 -> rows 0..127
    const int n_l = t & 63;
    const int qu = widu;                        // ph2 j-octet (scalar)
    // scalar X base: waves 0-3 -> X1 rows widu*16.., waves 4-7 -> X2
    const char* Xrow = (const char*)(widu >= 4 ? X2 : X1)
                     + (size_t)((widu & 3) * 16) * (size_t)(NN * 64);
    const int rb64 = r8 * NN * 64;              // per-lane row offset (int-safe)
    const float sc = 1.0f / 65025.0f;
    const unsigned short* Tp = Tsrc + (size_t)pair * NN;

    int lofA, lofB, lofC, lofD;
    int4 cx0, cx1, cx2, cx3, nx0, nx1, nx2, nx3;

    // phase 2: bilinear; Ft[sb] -> redp[sb]
    auto ph2 = [&](int sb, int cn) {
        float part0 = 0.f, part1 = 0.f;
        if (n_l < cn) {
            f16x2 zero = {(_Float16)0, (_Float16)0};
            f16x2 f1v[8];
            f16x2 eu = zero;
#pragma unroll
            for (int jj = 0; jj < 8; ++jj) {
                f1v[jj] = bc_h2(Ft[sb][qu * 8 + jj][n_l]);
                eu += bc_h2(pi1_pk[qu * 8 + jj]) * f1v[jj];  // s_load
            }
            f16x2 euv = zero, ev = zero;
#pragma unroll 8
            for (int k2 = 0; k2 < 64; ++k2) {
                f16x2 f2 = bc_h2(Ft[sb][64 + k2][n_l]);
                const uint4* pt = (const uint4*)(pi_t_pk + k2 * 64 + qu * 8);
                uint4 w0 = pt[0], w1 = pt[1];  // scalar addr -> s_load_dwordx4
                f16x2 ts = bc_h2(w0.x) * f1v[0] + bc_h2(w0.y) * f1v[1] +
                           bc_h2(w0.z) * f1v[2] + bc_h2(w0.w) * f1v[3] +
                           bc_h2(w1.x) * f1v[4] + bc_h2(w1.y) * f1v[5] +
                           bc_h2(w1.z) * f1v[6] + bc_h2(w1.w) * f1v[7];
                euv += f2 * ts;
                if (qu == 0) ev += bc_h2(pi2_pk[k2]) * f2;
            }
            part0 = (float)eu[0] - (float)euv[0];
            part1 = (float)eu[1] - (float)euv[1];
            if (qu == 0) {
                part0 += (float)ev[0];
                part1 += (float)ev[1];
            }
        }
        *(float2*)&redp[sb][qu][n_l][0] = make_float2(part0, part1);
    };

    // combine + soft-OR + store (threads < 128; lane pair = one n, b = t&1)
    auto comb = [&](int pb, int nb, int cn) {
        if (t < 128) {
            int n = t >> 1, b = t & 1;
            if (n < cn) {
                float d = 0.f;
#pragma unroll
                for (int q8 = 0; q8 < 8; ++q8) d += redp[pb][q8][n][b];
                int gn = nb + n;
                float ap;
                if (ITER == 1) ap = a0[(size_t)(pair * 2 + b) * NN + gn];
                else ap = (float)((tab[gn] >> (8 * b)) & 255u) * (1.0f / 255.0f);
                float an = 1.0f - (1.0f - ap) * (1.0f - d);
                if (ITER == 1) {
                    unsigned int v = __float2uint_rn(__saturatef(an) * 255.0f) << (8 * b);
                    v = or_dpp_x1(v);
                    if (b == 0) Tdst[(size_t)pair * NN + gn] = (unsigned short)v;
                } else {
                    outP[(size_t)(pair * 2 + b) * NN + gn] = an;
                }
            }
        }
    };

    // ---- prologue: step-0 X loads hide under the tab fill ----
    ADDRC(bstart);
    LDXQ(cx0, cx1, cx2, cx3, lofA);
    __builtin_amdgcn_sched_barrier(0);
    for (int i = t; i < (NN / 2); i += 512)
        ((unsigned int*)tab)[i] = ((const unsigned int*)Tp)[i];
    __syncthreads();
    PH1CHUNK(0, 30);
    __syncthreads();

    // ---- pipelined regions: one barrier per chunk ----
    for (int r = 0; r < 3; ++r) {
        const int sb = r & 1, db = sb ^ 1;
        if (r < 2) {
            ADDRC(bstart + 30 * (r + 1));
            LDXQ(cx0, cx1, cx2, cx3, lofA);      // step 0 of next chunk, early
            __builtin_amdgcn_sched_barrier(0);
        }
        if (r > 0) comb(db, bstart + 30 * (r - 1), 30);
        {
            int cnr = bcnt - 30 * r; cnr = cnr > 30 ? 30 : cnr;
            ph2(sb, cnr);
        }
        if (r < 2) {
            int cn1 = bcnt - 30 * (r + 1); cn1 = cn1 > 30 ? 30 : cn1;
            PH1CHUNK(db, cn1);
        }
        __syncthreads();
    }
    comb(0, bstart + 60, bcnt - 60);
}

extern "C" void kernel_launch(void* const* d_in, const int* in_sizes, int n_in,
                              void* d_out, int out_size, void* d_ws, size_t ws_size,
                              hipStream_t stream) {
    const float* a0 = (const float*)d_in[0];
    const float* W = (const float*)d_in[1];
    const int* X1 = (const int*)d_in[2];   // int64 in ref -> int32 on device
    const int* X2 = (const int*)d_in[3];
    float* out = (float*)d_out;

    // ws: (unused @0, 16,384) | pi_t_pk @16,384 | pi1_pk @32,768 | pi2_pk @33,024
    // | T0 @33,280 ([2][NN] u16 = 80,000) | T1 @113,280 (80,000)
    if (ws_size < (size_t)193280) return;
    unsigned int* pi_t    = (unsigned int*)((char*)d_ws + 16384);
    unsigned int* pi1_pk  = (unsigned int*)((char*)d_ws + 32768);
    unsigned int* pi2_pk  = (unsigned int*)((char*)d_ws + 33024);
    unsigned short* T0    = (unsigned short*)((char*)d_ws + 33280);
    unsigned short* T1    = (unsigned short*)((char*)d_ws + 113280);

    setup_kernel<<<21, 1024, 0, stream>>>(W, a0, pi_t, pi1_pk, pi2_pk, T0);
    fused_iter<1><<<512, 512, 0, stream>>>(T0, X1, X2, pi_t, pi1_pk, pi2_pk,
                                           a0, T1, nullptr);
    fused_iter<2><<<512, 512, 0, stream>>>(T1, X1, X2, pi_t, pi1_pk, pi2_pk,
                                           nullptr, nullptr, out);
}